// Round 3
// baseline (708.060 us; speedup 1.0000x reference)
//
#include <hip/hip_runtime.h>
#include <hip/hip_bf16.h>
#include <math.h>

// ---------------- problem constants ----------------
#define T_TOK 2048
#define H_DIM 512
#define E_NUM 16
#define TOPK  2
#define I_DIM 2048
#define IS_DIM 1024
#define NROWS (T_TOK * TOPK)   // 4096 routed (token,expert) rows

typedef __attribute__((ext_vector_type(8))) short bf16x8;
typedef __attribute__((ext_vector_type(4))) float f32x4;
typedef unsigned short ushort_t;

static __device__ __forceinline__ unsigned short f2bf(float f) {
  unsigned int u = __float_as_uint(f);
  unsigned int r = (u + 0x7fffu + ((u >> 16) & 1u)) >> 16;   // RNE
  return (unsigned short)r;
}

static __device__ __forceinline__ bf16x8 pack8(float4 a, float4 b) {
  bf16x8 v;
  v[0] = (short)f2bf(a.x); v[1] = (short)f2bf(a.y);
  v[2] = (short)f2bf(a.z); v[3] = (short)f2bf(a.w);
  v[4] = (short)f2bf(b.x); v[5] = (short)f2bf(b.y);
  v[6] = (short)f2bf(b.z); v[7] = (short)f2bf(b.w);
  return v;
}

// ---------------- 0) fp32 -> bf16 conversion (x only) ----------------
__global__ __launch_bounds__(256) void conv_kernel(const float* __restrict__ s,
                                                   ushort_t* __restrict__ d, int n8) {
  int i = blockIdx.x * 256 + threadIdx.x;
  int stride = gridDim.x * 256;
  for (; i < n8; i += stride) {
    float4 f0 = ((const float4*)s)[(size_t)i * 2];
    float4 f1 = ((const float4*)s)[(size_t)i * 2 + 1];
    ((bf16x8*)d)[i] = pack8(f0, f1);
  }
}

// ---------------- 1) gate: logits -> softmax -> top2 -> counts ----------------
__global__ __launch_bounds__(64) void gate_kernel(
    const float* __restrict__ x, const float* __restrict__ gw,
    int* __restrict__ topk_idx, float* __restrict__ topk_w, int* __restrict__ counts)
{
  int t = blockIdx.x;
  int lane = threadIdx.x;
  __shared__ float xs[H_DIM];
  __shared__ float lg[E_NUM];
  const float4* xr = (const float4*)(x + (size_t)t * H_DIM);
  ((float4*)xs)[lane] = xr[lane];
  ((float4*)xs)[lane + 64] = xr[lane + 64];
  __syncthreads();
  if (lane < E_NUM) {
    const float* w = gw + (size_t)lane * H_DIM;
    float acc = 0.f;
    #pragma unroll 8
    for (int h = 0; h < H_DIM; h++) acc += xs[h] * w[h];
    lg[lane] = acc;
  }
  __syncthreads();
  if (lane == 0) {
    float mx = lg[0];
    #pragma unroll
    for (int e = 1; e < E_NUM; e++) mx = fmaxf(mx, lg[e]);
    float sc[E_NUM];
    float sum = 0.f;
    #pragma unroll
    for (int e = 0; e < E_NUM; e++) { sc[e] = expf(lg[e] - mx); sum += sc[e]; }
    float inv = 1.f / sum;
    float m1 = -1.f, m2 = -1.f; int i1 = 0, i2 = 0;
    #pragma unroll
    for (int e = 0; e < E_NUM; e++) {
      float s = sc[e] * inv;
      if (s > m1)      { m2 = m1; i2 = i1; m1 = s; i1 = e; }
      else if (s > m2) { m2 = s; i2 = e; }
    }
    topk_idx[t * 2] = i1; topk_idx[t * 2 + 1] = i2;
    topk_w[t * 2] = m1;  topk_w[t * 2 + 1] = m2;
    atomicAdd(&counts[i1], 1);
    atomicAdd(&counts[i2], 1);
  }
}

// ---------------- 2) exclusive scan over 16 counts ----------------
__global__ void offsets_kernel(const int* __restrict__ counts,
                               int* __restrict__ offsets, int* __restrict__ cursor)
{
  if (threadIdx.x == 0) {
    int acc = 0;
    #pragma unroll
    for (int e = 0; e < E_NUM; e++) { offsets[e] = acc; acc += counts[e]; }
    offsets[E_NUM] = acc;
  }
  if (threadIdx.x < E_NUM) cursor[threadIdx.x] = 0;
}

// ---------------- 3) scatter tokens into per-expert lists ----------------
__global__ __launch_bounds__(256) void scatter_kernel(
    const int* __restrict__ topk_idx, const float* __restrict__ topk_w,
    const int* __restrict__ offsets, int* __restrict__ cursor,
    int* __restrict__ row_token, float* __restrict__ row_w)
{
  int t = blockIdx.x * 256 + threadIdx.x;
  if (t >= T_TOK) return;
  #pragma unroll
  for (int k = 0; k < TOPK; k++) {
    int e = topk_idx[t * 2 + k];
    int pos = atomicAdd(&cursor[e], 1);
    int row = offsets[e] + pos;
    row_token[row] = t;
    row_w[row] = topk_w[t * 2 + k];
  }
}

// ---------------- 4) grouped GU GEMM: inter = silu(X*Wg^T).*(X*Wu^T) ----------
// BM=128, BN=64, BK=64, 256 thr (4 waves, each 64x32 of both g and u).
// Reg-staged: A from bf16 x, B fp32->bf16 inline. 2-phase pipeline,
// double-buffered LDS, ONE barrier per K-step. Chunk-XOR swizzle (c^(row&7)).
#define GU_BM 128
#define GU_BN 64
#define GU_BK 64
#define GU_NK (H_DIM / GU_BK)   // 8

__global__ __launch_bounds__(256) void gu3_kernel(
    const ushort_t* __restrict__ xb,                       // [T,512] bf16
    const float* __restrict__ wg_all,
    const float* __restrict__ wu_all,                      // [E,Idim,512] fp32
    ushort_t* __restrict__ inter,
    const int* __restrict__ row_token,                     // null -> identity rows
    const int* __restrict__ counts,                        // null -> cnt=total_rows
    const int* __restrict__ offsets,                       // null -> base=0
    int Idim, int total_rows, int maxrt)
{
  int e  = blockIdx.x / maxrt;
  int rt = blockIdx.x % maxrt;
  int cnt = counts ? counts[e] : total_rows;
  int n0 = rt * GU_BM;
  if (n0 >= cnt) return;
  int base = offsets ? offsets[e] : 0;
  int c0 = blockIdx.y * GU_BN;
  const float* wg = wg_all + (size_t)e * Idim * H_DIM;
  const float* wu = wu_all + (size_t)e * Idim * H_DIM;

  __shared__ __align__(16) ushort_t As[2][GU_BM * GU_BK];   // 2x16KB
  __shared__ __align__(16) ushort_t Bgs[2][GU_BN * GU_BK];  // 2x8KB
  __shared__ __align__(16) ushort_t Bus[2][GU_BN * GU_BK];  // 2x8KB

  int tid = threadIdx.x, wid = tid >> 6, lane = tid & 63;

  // A staging: row = tid>>1 (0..127), 4 chunks starting at (tid&1)*4
  int arow = tid >> 1;
  int acb  = (tid & 1) * 4;
  int ar = n0 + arow; if (ar >= cnt) ar = cnt - 1;
  int atok = row_token ? row_token[base + ar] : (base + ar);
  const ushort_t* asrc = xb + (size_t)atok * H_DIM;
  int awoff[4];
  #pragma unroll
  for (int i = 0; i < 4; i++)
    awoff[i] = arow * GU_BK + (((acb + i) ^ (arow & 7)) << 3);

  // B staging: row = tid>>2 (0..63), q = tid&3 -> f32 cols q*16..+15
  int brow = tid >> 2, bq = tid & 3;
  const float* bgsrc = wg + (size_t)(c0 + brow) * H_DIM + bq * 16;
  const float* busrc = wu + (size_t)(c0 + brow) * H_DIM + bq * 16;
  int bwoff0 = brow * GU_BK + (((2 * bq    ) ^ (brow & 7)) << 3);
  int bwoff1 = brow * GU_BK + (((2 * bq + 1) ^ (brow & 7)) << 3);

  int wr = (wid >> 1) * 64, wc = (wid & 1) * 32;
  int fr = lane & 15, g = lane >> 4;

  f32x4 accg[4][2] = {}, accu[4][2] = {};
  bf16x8 rA[4]; float4 rG[4], rU[4];

  auto issue = [&](int k0) {
    #pragma unroll
    for (int i = 0; i < 4; i++) rA[i] = *(const bf16x8*)(asrc + k0 + (acb + i) * 8);
    #pragma unroll
    for (int i = 0; i < 4; i++) rG[i] = *(const float4*)(bgsrc + k0 + i * 4);
    #pragma unroll
    for (int i = 0; i < 4; i++) rU[i] = *(const float4*)(busrc + k0 + i * 4);
  };

  issue(0);
  int cur = 0;
  for (int kk = 0; kk < GU_NK; kk++) {
    ushort_t* a  = As[cur];
    ushort_t* bg = Bgs[cur];
    ushort_t* bu = Bus[cur];
    #pragma unroll
    for (int i = 0; i < 4; i++) *(bf16x8*)&a[awoff[i]] = rA[i];
    *(bf16x8*)&bg[bwoff0] = pack8(rG[0], rG[1]);
    *(bf16x8*)&bg[bwoff1] = pack8(rG[2], rG[3]);
    *(bf16x8*)&bu[bwoff0] = pack8(rU[0], rU[1]);
    *(bf16x8*)&bu[bwoff1] = pack8(rU[2], rU[3]);
    __syncthreads();
    if (kk + 1 < GU_NK) issue((kk + 1) * GU_BK);
    #pragma unroll
    for (int s = 0; s < 2; s++) {
      bf16x8 af[4], bgf[2], buf2[2];
      #pragma unroll
      for (int m = 0; m < 4; m++) {
        int R = wr + m * 16 + fr;
        af[m] = *(const bf16x8*)&a[R * GU_BK + (((s * 4 + g) ^ (R & 7)) << 3)];
      }
      #pragma unroll
      for (int n = 0; n < 2; n++) {
        int C = wc + n * 16 + fr;
        int off = C * GU_BK + (((s * 4 + g) ^ (C & 7)) << 3);
        bgf[n]  = *(const bf16x8*)&bg[off];
        buf2[n] = *(const bf16x8*)&bu[off];
      }
      #pragma unroll
      for (int m = 0; m < 4; m++) {
        #pragma unroll
        for (int n = 0; n < 2; n++) {
          accg[m][n] = __builtin_amdgcn_mfma_f32_16x16x32_bf16(af[m], bgf[n],  accg[m][n], 0, 0, 0);
          accu[m][n] = __builtin_amdgcn_mfma_f32_16x16x32_bf16(af[m], buf2[n], accu[m][n], 0, 0, 0);
        }
      }
    }
    cur ^= 1;
  }

  // epilogue: silu(g)*u -> bf16 inter
  #pragma unroll
  for (int m = 0; m < 4; m++) {
    #pragma unroll
    for (int j = 0; j < 4; j++) {
      int r = wr + m * 16 + g * 4 + j;
      if (n0 + r < cnt) {
        size_t orow = (size_t)(base + n0 + r) * Idim;
        #pragma unroll
        for (int n = 0; n < 2; n++) {
          float gg = accg[m][n][j], uu = accu[m][n][j];
          float s = (gg / (1.f + expf(-gg))) * uu;
          inter[orow + c0 + wc + n * 16 + fr] = f2bf(s);
        }
      }
    }
  }
}

// ---------------- 5) down GEMM: out (+)= (inter * Wd^T) [* weight] ------------
// BM=64, BN=64, BK=128, 256 thr (4 waves 2x2 of 32x32). Same 2-phase pipeline.
#define DN_BM 64
#define DN_BN 64
#define DN_BK 128

__global__ __launch_bounds__(256) void down3_kernel(
    const ushort_t* __restrict__ inter,                    // [rows,Kdim] bf16
    const float* __restrict__ wd_all,                      // [E,H,Kdim] fp32
    float* __restrict__ outp,
    const int* __restrict__ row_token,                     // null -> identity rows
    const float* __restrict__ row_w,                       // null -> store path
    const int* __restrict__ counts, const int* __restrict__ offsets,
    int Kdim, int total_rows, int maxrt)
{
  int e  = blockIdx.x / maxrt;
  int rt = blockIdx.x % maxrt;
  int cnt = counts ? counts[e] : total_rows;
  int n0 = rt * DN_BM;
  if (n0 >= cnt) return;
  int base = offsets ? offsets[e] : 0;
  int c0 = blockIdx.y * DN_BN;
  const float* wd = wd_all + (size_t)e * H_DIM * Kdim;
  int nk = Kdim / DN_BK;

  __shared__ __align__(16) ushort_t As[2][DN_BM * DN_BK];   // 2x16KB
  __shared__ __align__(16) ushort_t Bs[2][DN_BN * DN_BK];   // 2x16KB
  __shared__ int   toks[DN_BM];
  __shared__ float rws[DN_BM];

  int tid = threadIdx.x, wid = tid >> 6, lane = tid & 63;
  if (tid < DN_BM) {
    int r = n0 + tid;
    if (r < cnt) {
      int row = base + r;
      toks[tid] = row_token ? row_token[row] : row;
      rws[tid]  = row_w ? row_w[row] : 1.f;
    } else { toks[tid] = 0; rws[tid] = 0.f; }
  }

  // A staging: row = tid>>2 (0..63), 4 chunks starting at (tid&3)*4 (16 chunks/row)
  int arow = tid >> 2;
  int acb  = (tid & 3) * 4;
  const ushort_t* asrc = inter + (size_t)(base + n0 + arow) * Kdim;  // may overread; stores guarded
  int awoff[4];
  #pragma unroll
  for (int i = 0; i < 4; i++)
    awoff[i] = arow * DN_BK + (((acb + i) ^ (arow & 7)) << 3);

  // B staging: row = tid>>2, f32 cols (tid&3)*32 .. +31 (8 float4)
  int brow = arow, bq = tid & 3;
  const float* bsrc = wd + (size_t)(c0 + brow) * Kdim + bq * 32;
  int bwoff[4];
  #pragma unroll
  for (int i = 0; i < 4; i++)
    bwoff[i] = brow * DN_BK + (((bq * 4 + i) ^ (brow & 7)) << 3);

  int wr = (wid >> 1) * 32, wc = (wid & 1) * 32;
  int fr = lane & 15, g = lane >> 4;

  f32x4 acc[2][2] = {};
  bf16x8 rA[4]; float4 rB[8];

  auto issue = [&](int k0) {
    #pragma unroll
    for (int i = 0; i < 4; i++) rA[i] = *(const bf16x8*)(asrc + k0 + (acb + i) * 8);
    #pragma unroll
    for (int i = 0; i < 8; i++) rB[i] = *(const float4*)(bsrc + k0 + i * 4);
  };

  issue(0);
  int cur = 0;
  for (int kk = 0; kk < nk; kk++) {
    ushort_t* a = As[cur];
    ushort_t* b = Bs[cur];
    #pragma unroll
    for (int i = 0; i < 4; i++) *(bf16x8*)&a[awoff[i]] = rA[i];
    #pragma unroll
    for (int i = 0; i < 4; i++) *(bf16x8*)&b[bwoff[i]] = pack8(rB[2 * i], rB[2 * i + 1]);
    __syncthreads();
    if (kk + 1 < nk) issue((kk + 1) * DN_BK);
    #pragma unroll
    for (int s = 0; s < 4; s++) {
      bf16x8 af[2], bf[2];
      #pragma unroll
      for (int m = 0; m < 2; m++) {
        int R = wr + m * 16 + fr;
        af[m] = *(const bf16x8*)&a[R * DN_BK + (((s * 4 + g) ^ (R & 7)) << 3)];
      }
      #pragma unroll
      for (int n = 0; n < 2; n++) {
        int C = wc + n * 16 + fr;
        bf[n] = *(const bf16x8*)&b[C * DN_BK + (((s * 4 + g) ^ (C & 7)) << 3)];
      }
      #pragma unroll
      for (int m = 0; m < 2; m++)
        #pragma unroll
        for (int n = 0; n < 2; n++)
          acc[m][n] = __builtin_amdgcn_mfma_f32_16x16x32_bf16(af[m], bf[n], acc[m][n], 0, 0, 0);
    }
    cur ^= 1;
  }

  #pragma unroll
  for (int m = 0; m < 2; m++) {
    #pragma unroll
    for (int j = 0; j < 4; j++) {
      int r = wr + m * 16 + g * 4 + j;
      if (n0 + r < cnt) {
        int tk = toks[r];
        float rw = rws[r];
        #pragma unroll
        for (int n = 0; n < 2; n++) {
          int col = c0 + wc + n * 16 + fr;
          float v = acc[m][n][j];
          if (row_w) atomicAdd(&outp[(size_t)tk * H_DIM + col], v * rw);
          else       outp[(size_t)tk * H_DIM + col] = v;
        }
      }
    }
  }
}

// ---------------- launch ----------------
extern "C" void kernel_launch(void* const* d_in, const int* in_sizes, int n_in,
                              void* d_out, int out_size, void* d_ws, size_t ws_size,
                              hipStream_t stream) {
  const float* x       = (const float*)d_in[0];
  const float* gate_w  = (const float*)d_in[1];
  const float* w_gate  = (const float*)d_in[2];
  const float* w_up    = (const float*)d_in[3];
  const float* w_down  = (const float*)d_in[4];
  const float* sw_gate = (const float*)d_in[5];
  const float* sw_up   = (const float*)d_in[6];
  const float* sw_down = (const float*)d_in[7];
  float* out = (float*)d_out;

  char* ws = (char*)d_ws;
  int*   counts    = (int*)ws;                    // 16 ints
  int*   cursor    = (int*)(ws + 64);             // 16 ints
  int*   offsets   = (int*)(ws + 128);            // 17 ints
  int*   topk_idx  = (int*)(ws + 256);            // 4096 ints
  float* topk_w    = (float*)(ws + 16640);        // 4096 f32
  int*   row_token = (int*)(ws + 33024);          // 4096 ints
  float* row_w     = (float*)(ws + 49408);        // 4096 f32
  size_t off = 65792;
  ushort_t* xb      = (ushort_t*)(ws + off); off += (size_t)T_TOK * H_DIM * 2;   // 2 MiB
  ushort_t* inter_r = (ushort_t*)(ws + off); off += (size_t)NROWS * I_DIM * 2;   // 16 MiB
  ushort_t* inter_s = (ushort_t*)(ws + off); off += (size_t)T_TOK * IS_DIM * 2;  // 4 MiB

  hipMemsetAsync(counts, 0, 64, stream);
  gate_kernel<<<T_TOK, 64, 0, stream>>>(x, gate_w, topk_idx, topk_w, counts);
  offsets_kernel<<<1, 64, 0, stream>>>(counts, offsets, cursor);
  scatter_kernel<<<(T_TOK + 255) / 256, 256, 0, stream>>>(topk_idx, topk_w, offsets, cursor,
                                                          row_token, row_w);
  conv_kernel<<<512, 256, 0, stream>>>(x, xb, T_TOK * H_DIM / 8);

  // routed GU: grid (E*16 row tiles of 128, I/64 col tiles)
  gu3_kernel<<<dim3(E_NUM * 16, I_DIM / 64), 256, 0, stream>>>(
      xb, w_gate, w_up, inter_r, row_token, counts, offsets, I_DIM, NROWS, 16);
  // shared GU: dense 2048 rows
  gu3_kernel<<<dim3(16, IS_DIM / 64), 256, 0, stream>>>(
      xb, sw_gate, sw_up, inter_s, nullptr, nullptr, nullptr, IS_DIM, T_TOK, 16);
  // shared down first (plain stores initialize out fully)
  down3_kernel<<<dim3(32, H_DIM / 64), 256, 0, stream>>>(
      inter_s, sw_down, out, nullptr, nullptr, nullptr, nullptr, IS_DIM, T_TOK, 32);
  // routed down: weighted atomic accumulation into out
  down3_kernel<<<dim3(E_NUM * 32, H_DIM / 64), 256, 0, stream>>>(
      inter_r, w_down, out, row_token, row_w, counts, offsets, I_DIM, NROWS, 32);
}